// Round 3
// baseline (2223.492 us; speedup 1.0000x reference)
//
#include <hip/hip_runtime.h>

// BranchingGNN, fp32. R3: latency-bound gather fixed via 32-lane/edge float4
// gather (4 edges in flight per wave, 2-deep unroll), LDS group-partials,
// fused H×H GEMM + relu + residual. CSR built once per launch with a
// shfl-based exclusive scan (R2's barrier-heavy scan was ~100+ µs).

static constexpr int HDIM = 128;

// ---------------- initial projection: out = relu(X @ W + b), K=64 -------------
template<int K, int R>
__global__ __launch_bounds__(128) void gemm_relu_kernel(
    const float* __restrict__ X, const float* __restrict__ W,
    const float* __restrict__ b, float* __restrict__ out, int nrows)
{
    __shared__ float xs[R][K];
    const int j = threadIdx.x;
    const int r0 = blockIdx.x * R;
    const int total = R * K;
    for (int t = j; t < total; t += 128) {
        const int rr = t / K, kk = t % K;
        const int r = r0 + rr;
        xs[rr][kk] = (r < nrows) ? X[(size_t)r * K + kk] : 0.f;
    }
    __syncthreads();
    float acc[R];
    const float bj = b[j];
    #pragma unroll
    for (int i = 0; i < R; ++i) acc[i] = bj;
    #pragma unroll 8
    for (int k = 0; k < K; ++k) {
        const float w = W[k * HDIM + j];
        #pragma unroll
        for (int i = 0; i < R; ++i) acc[i] = fmaf(xs[i][k], w, acc[i]);
    }
    #pragma unroll
    for (int i = 0; i < R; ++i) {
        const int r = r0 + i;
        if (r < nrows) out[(size_t)r * HDIM + j] = fmaxf(acc[i], 0.f);
    }
}

// ---------------- CSR build ---------------------------------------------------
__global__ __launch_bounds__(256) void count_kernel(
    const int* __restrict__ i_idx, const int* __restrict__ p_idx,
    int* __restrict__ cnt_i, int* __restrict__ cnt_p, int E)
{
    const int e = (blockIdx.x * 256 + threadIdx.x) * 4;
    if (e + 3 < E) {
        const int4 a = *(const int4*)(i_idx + e);
        const int4 b = *(const int4*)(p_idx + e);
        atomicAdd(&cnt_i[a.x], 1); atomicAdd(&cnt_i[a.y], 1);
        atomicAdd(&cnt_i[a.z], 1); atomicAdd(&cnt_i[a.w], 1);
        atomicAdd(&cnt_p[b.x], 1); atomicAdd(&cnt_p[b.y], 1);
        atomicAdd(&cnt_p[b.z], 1); atomicAdd(&cnt_p[b.w], 1);
    } else {
        for (int k = e; k < E; ++k) {
            atomicAdd(&cnt_i[i_idx[k]], 1);
            atomicAdd(&cnt_p[p_idx[k]], 1);
        }
    }
}

// Single-block exclusive scan, shfl-based. out[len] = total. ~3 barriers/4096.
__global__ __launch_bounds__(1024) void exscan_kernel(
    const int* __restrict__ in, int* __restrict__ out, int len)
{
    __shared__ int wsum[16];
    __shared__ int carry_s;
    const int tid = threadIdx.x, lane = tid & 63, wid = tid >> 6;
    if (tid == 0) carry_s = 0;
    __syncthreads();
    for (int base = 0; base < len; base += 4096) {
        const int idx = base + tid * 4;
        int4 v = make_int4(0, 0, 0, 0);
        if (idx + 3 < len) {
            v = *(const int4*)(in + idx);
        } else if (idx < len) {
            v.x = in[idx];
            if (idx + 1 < len) v.y = in[idx + 1];
            if (idx + 2 < len) v.z = in[idx + 2];
        }
        const int s = v.x + v.y + v.z + v.w;
        int sc = s;                      // inclusive wave scan of thread sums
        #pragma unroll
        for (int off = 1; off < 64; off <<= 1) {
            const int t = __shfl_up(sc, off, 64);
            if (lane >= off) sc += t;
        }
        if (lane == 63) wsum[wid] = sc;
        __syncthreads();
        if (wid == 0) {                  // scan the 16 wave totals
            const int ws = (lane < 16) ? wsum[lane] : 0;
            int wsc = ws;
            #pragma unroll
            for (int off = 1; off < 16; off <<= 1) {
                const int t = __shfl_up(wsc, off, 64);
                if (lane >= off) wsc += t;
            }
            if (lane < 16) wsum[lane] = wsc - ws;   // exclusive wave prefix
        }
        __syncthreads();
        const int excl = carry_s + wsum[wid] + (sc - s);
        if (idx < len) {
            out[idx] = excl;
            if (idx + 1 < len) out[idx + 1] = excl + v.x;
            if (idx + 2 < len) out[idx + 2] = excl + v.x + v.y;
            if (idx + 3 < len) out[idx + 3] = excl + v.x + v.y + v.z;
        }
        __syncthreads();                 // everyone done reading carry_s/wsum
        if (tid == 1023) carry_s = excl + s;
        __syncthreads();
    }
    if (tid == 0) out[len] = carry_s;
}

__global__ __launch_bounds__(256) void fill_kernel(
    const int* __restrict__ i_idx, const int* __restrict__ p_idx,
    const int* __restrict__ row_p, const int* __restrict__ row_i,
    int* __restrict__ cur_p, int* __restrict__ cur_i,
    int* __restrict__ esrc_p, int* __restrict__ esrc_i, int E)
{
    const int e0 = (blockIdx.x * 256 + threadIdx.x) * 4;
    if (e0 >= E) return;
    int4 a, b;
    if (e0 + 3 < E) {
        a = *(const int4*)(i_idx + e0);
        b = *(const int4*)(p_idx + e0);
    } else {
        a = make_int4(i_idx[e0], 0, 0, 0); b = make_int4(p_idx[e0], 0, 0, 0);
        if (e0 + 1 < E) { a.y = i_idx[e0 + 1]; b.y = p_idx[e0 + 1]; }
        if (e0 + 2 < E) { a.z = i_idx[e0 + 2]; b.z = p_idx[e0 + 2]; }
    }
    const int ii[4] = {a.x, a.y, a.z, a.w};
    const int pp[4] = {b.x, b.y, b.z, b.w};
    #pragma unroll
    for (int k = 0; k < 4; ++k) {
        if (e0 + k >= E) break;
        const int sp = atomicAdd(&cur_p[pp[k]], 1);
        esrc_p[row_p[pp[k]] + sp] = ii[k];
        const int si = atomicAdd(&cur_i[ii[k]], 1);
        esrc_i[row_i[ii[k]] + si] = pp[k];
    }
}

// ---------------- fused gather + GEMM + relu + residual + relu ----------------
// Block = 256 threads. Gather: 8 groups of 32 lanes; group g handles edges
// s0+g, s0+g+8, ... of each of the block's R=8 destination rows; each lane
// loads float4 (cols 4l..4l+3). Partials in LDS [R][8][128], reduced once.
// GEMM: thread (half=tid>>7, j=tid&127) owns rows half*4..half*4+3, col j.
template<int R>
__global__ __launch_bounds__(256) void gather_update_kernel(
    const float* __restrict__ src, const int* __restrict__ row,
    const int* __restrict__ esrc, const float* __restrict__ W,
    const float* __restrict__ b, float* __restrict__ hdst, int ndst)
{
    __shared__ float part[R][8][HDIM];          // 32 KB
    const int tid = threadIdx.x;
    const int g = tid >> 5;                     // edge group 0..7
    const int l = tid & 31;                     // lane in group
    const int d0 = blockIdx.x * R;

    #pragma unroll
    for (int r = 0; r < R; ++r) {
        const int d = d0 + r;
        float4 acc0 = {0.f, 0.f, 0.f, 0.f};
        float4 acc1 = {0.f, 0.f, 0.f, 0.f};
        if (d < ndst) {
            const int s1 = row[d + 1];
            int e = row[d] + g;
            for (; e + 8 < s1; e += 16) {       // 2 edges in flight per group
                const int i0 = esrc[e];
                const int i1 = esrc[e + 8];
                const float4 v0 = ((const float4*)(src + (size_t)i0 * HDIM))[l];
                const float4 v1 = ((const float4*)(src + (size_t)i1 * HDIM))[l];
                acc0.x += v0.x; acc0.y += v0.y; acc0.z += v0.z; acc0.w += v0.w;
                acc1.x += v1.x; acc1.y += v1.y; acc1.z += v1.z; acc1.w += v1.w;
            }
            if (e < s1) {
                const int i0 = esrc[e];
                const float4 v0 = ((const float4*)(src + (size_t)i0 * HDIM))[l];
                acc0.x += v0.x; acc0.y += v0.y; acc0.z += v0.z; acc0.w += v0.w;
            }
            acc0.x += acc1.x; acc0.y += acc1.y; acc0.z += acc1.z; acc0.w += acc1.w;
        }
        ((float4*)part[r][g])[l] = acc0;
    }
    __syncthreads();

    const int j = tid & 127;
    const int half = tid >> 7;
    // reduce 8 group-partials -> part[r][0][j]; (r,j) owned by one thread
    #pragma unroll
    for (int rr = 0; rr < R / 2; ++rr) {
        const int r = half * (R / 2) + rr;
        float s = 0.f;
        #pragma unroll
        for (int gg = 0; gg < 8; ++gg) s += part[r][gg][j];
        part[r][0][j] = s;
    }
    __syncthreads();

    float acc[R / 2];
    const float bj = b[j];
    #pragma unroll
    for (int rr = 0; rr < R / 2; ++rr) acc[rr] = bj;
    for (int kk = 0; kk < HDIM / 4; ++kk) {
        float4 mv[R / 2];
        #pragma unroll
        for (int rr = 0; rr < R / 2; ++rr)
            mv[rr] = ((const float4*)part[half * (R / 2) + rr][0])[kk];  // broadcast
        const float w0 = W[(kk * 4 + 0) * HDIM + j];
        const float w1 = W[(kk * 4 + 1) * HDIM + j];
        const float w2 = W[(kk * 4 + 2) * HDIM + j];
        const float w3 = W[(kk * 4 + 3) * HDIM + j];
        #pragma unroll
        for (int rr = 0; rr < R / 2; ++rr) {
            acc[rr] = fmaf(mv[rr].x, w0, acc[rr]);
            acc[rr] = fmaf(mv[rr].y, w1, acc[rr]);
            acc[rr] = fmaf(mv[rr].z, w2, acc[rr]);
            acc[rr] = fmaf(mv[rr].w, w3, acc[rr]);
        }
    }
    #pragma unroll
    for (int rr = 0; rr < R / 2; ++rr) {
        const int d = d0 + half * (R / 2) + rr;
        if (d < ndst) {
            const float upd = fmaxf(acc[rr], 0.f);
            const float h = hdst[(size_t)d * HDIM + j];
            hdst[(size_t)d * HDIM + j] = fmaxf(h + upd, 0.f);
        }
    }
}

extern "C" void kernel_launch(void* const* d_in, const int* in_sizes, int n_in,
                              void* d_out, int out_size, void* d_ws, size_t ws_size,
                              hipStream_t stream)
{
    const float* item_feat = (const float*)d_in[0];   // [n,64]
    const float* pat_feat  = (const float*)d_in[1];   // [m,64]
    const int*   i_idx     = (const int*)d_in[2];     // [E]
    const int*   p_idx     = (const int*)d_in[3];     // [E]
    const float* W_item    = (const float*)d_in[4];
    const float* b_item    = (const float*)d_in[5];
    const float* W_pat     = (const float*)d_in[6];
    const float* b_pat     = (const float*)d_in[7];
    const float* W_i2p     = (const float*)d_in[8];
    const float* b_i2p     = (const float*)d_in[9];
    const float* W_p2i     = (const float*)d_in[10];
    const float* b_p2i     = (const float*)d_in[11];

    const int n = in_sizes[0] / 64;
    const int m = in_sizes[1] / 64;
    const int E = in_sizes[2];

    float* h_item = (float*)d_out;                    // [n,128]
    float* h_pat  = (float*)d_out + (size_t)n * HDIM; // [m,128]

    // ws (ints): [cur_p m][cur_i n][row_p m+1][row_i n+1][esrc_p E][esrc_i E]
    int* cur_p  = (int*)d_ws;
    int* cur_i  = cur_p + m;
    int* row_p  = cur_i + n;
    int* row_i  = row_p + (m + 1);
    int* esrc_p = row_i + (n + 1);
    int* esrc_i = esrc_p + E;

    constexpr int RG = 8;
    gemm_relu_kernel<64, RG><<<(n + RG - 1) / RG, 128, 0, stream>>>(
        item_feat, W_item, b_item, h_item, n);
    gemm_relu_kernel<64, RG><<<(m + RG - 1) / RG, 128, 0, stream>>>(
        pat_feat, W_pat, b_pat, h_pat, m);

    // ---- CSR build (once; indices static across rounds) ----
    const int e4blocks = (E + 1023) / 1024;
    hipMemsetAsync(cur_p, 0, (size_t)(m + n) * sizeof(int), stream);
    count_kernel<<<e4blocks, 256, 0, stream>>>(i_idx, p_idx, cur_i, cur_p, E);
    exscan_kernel<<<1, 1024, 0, stream>>>(cur_p, row_p, m);
    exscan_kernel<<<1, 1024, 0, stream>>>(cur_i, row_i, n);
    hipMemsetAsync(cur_p, 0, (size_t)(m + n) * sizeof(int), stream);
    fill_kernel<<<e4blocks, 256, 0, stream>>>(i_idx, p_idx, row_p, row_i,
                                              cur_p, cur_i, esrc_p, esrc_i, E);

    // ---- 2 rounds fused gather+GEMM+update ----
    constexpr int R = 8;
    for (int round = 0; round < 2; ++round) {
        gather_update_kernel<R><<<(m + R - 1) / R, 256, 0, stream>>>(
            h_item, row_p, esrc_p, W_i2p, b_i2p, h_pat, m);
        gather_update_kernel<R><<<(n + R - 1) / R, 256, 0, stream>>>(
            h_pat, row_i, esrc_i, W_p2i, b_p2i, h_item, n);
    }
}

// Round 4
// 801.165 us; speedup vs baseline: 2.7753x; 2.7753x over previous
//
#include <hip/hip_runtime.h>

// BranchingGNN, fp32. R4: back to R2's low-VGPR "thread j owns column j"
// gather (36 VGPR, 48% occ), adding MLP via 4-way edge unroll with 4
// independent scalar accumulators (4 loads in flight/thread). R3's float4
// multi-group variant spilled (VGPR 256, 740 MB scratch writes) — reverted.
// CSR build once per launch; fast shfl exscan (both scans in one 2-block launch).

static constexpr int HDIM = 128;

// ---------------- initial projection: out = relu(X @ W + b), K=64 -------------
template<int K, int R>
__global__ __launch_bounds__(128) void gemm_relu_kernel(
    const float* __restrict__ X, const float* __restrict__ W,
    const float* __restrict__ b, float* __restrict__ out, int nrows)
{
    __shared__ float xs[R][K];
    const int j = threadIdx.x;
    const int r0 = blockIdx.x * R;
    const int total = R * K;
    for (int t = j; t < total; t += 128) {
        const int rr = t / K, kk = t % K;
        const int r = r0 + rr;
        xs[rr][kk] = (r < nrows) ? X[(size_t)r * K + kk] : 0.f;
    }
    __syncthreads();
    float acc[R];
    const float bj = b[j];
    #pragma unroll
    for (int i = 0; i < R; ++i) acc[i] = bj;
    #pragma unroll 8
    for (int k = 0; k < K; ++k) {
        const float w = W[k * HDIM + j];
        #pragma unroll
        for (int i = 0; i < R; ++i) acc[i] = fmaf(xs[i][k], w, acc[i]);
    }
    #pragma unroll
    for (int i = 0; i < R; ++i) {
        const int r = r0 + i;
        if (r < nrows) out[(size_t)r * HDIM + j] = fmaxf(acc[i], 0.f);
    }
}

// ---------------- CSR build ---------------------------------------------------
__global__ __launch_bounds__(256) void count_kernel(
    const int* __restrict__ i_idx, const int* __restrict__ p_idx,
    int* __restrict__ cnt_i, int* __restrict__ cnt_p, int E)
{
    const int e = (blockIdx.x * 256 + threadIdx.x) * 4;
    if (e + 3 < E) {
        const int4 a = *(const int4*)(i_idx + e);
        const int4 b = *(const int4*)(p_idx + e);
        atomicAdd(&cnt_i[a.x], 1); atomicAdd(&cnt_i[a.y], 1);
        atomicAdd(&cnt_i[a.z], 1); atomicAdd(&cnt_i[a.w], 1);
        atomicAdd(&cnt_p[b.x], 1); atomicAdd(&cnt_p[b.y], 1);
        atomicAdd(&cnt_p[b.z], 1); atomicAdd(&cnt_p[b.w], 1);
    } else {
        for (int k = e; k < E; ++k) {
            atomicAdd(&cnt_i[i_idx[k]], 1);
            atomicAdd(&cnt_p[p_idx[k]], 1);
        }
    }
}

// Two independent single-block exclusive scans in one launch (block 0 / block 1).
// out[len] = total. shfl wave scan + LDS wave-total scan; ~3 barriers / 4096 elems.
__global__ __launch_bounds__(1024) void exscan2_kernel(
    const int* __restrict__ in0, int* __restrict__ out0, int len0,
    const int* __restrict__ in1, int* __restrict__ out1, int len1)
{
    const int* __restrict__ in  = blockIdx.x ? in1  : in0;
    int* __restrict__ out       = blockIdx.x ? out1 : out0;
    const int len               = blockIdx.x ? len1 : len0;

    __shared__ int wsum[16];
    __shared__ int carry_s;
    const int tid = threadIdx.x, lane = tid & 63, wid = tid >> 6;
    if (tid == 0) carry_s = 0;
    __syncthreads();
    for (int base = 0; base < len; base += 4096) {
        const int idx = base + tid * 4;
        int4 v = make_int4(0, 0, 0, 0);
        if (idx + 3 < len) {
            v = *(const int4*)(in + idx);
        } else if (idx < len) {
            v.x = in[idx];
            if (idx + 1 < len) v.y = in[idx + 1];
            if (idx + 2 < len) v.z = in[idx + 2];
        }
        const int s = v.x + v.y + v.z + v.w;
        int sc = s;
        #pragma unroll
        for (int off = 1; off < 64; off <<= 1) {
            const int t = __shfl_up(sc, off, 64);
            if (lane >= off) sc += t;
        }
        if (lane == 63) wsum[wid] = sc;
        __syncthreads();
        if (wid == 0) {
            const int ws = (lane < 16) ? wsum[lane] : 0;
            int wsc = ws;
            #pragma unroll
            for (int off = 1; off < 16; off <<= 1) {
                const int t = __shfl_up(wsc, off, 64);
                if (lane >= off) wsc += t;
            }
            if (lane < 16) wsum[lane] = wsc - ws;
        }
        __syncthreads();
        const int excl = carry_s + wsum[wid] + (sc - s);
        if (idx < len) {
            out[idx] = excl;
            if (idx + 1 < len) out[idx + 1] = excl + v.x;
            if (idx + 2 < len) out[idx + 2] = excl + v.x + v.y;
            if (idx + 3 < len) out[idx + 3] = excl + v.x + v.y + v.z;
        }
        __syncthreads();
        if (tid == 1023) carry_s = excl + s;
        __syncthreads();
    }
    if (tid == 0) out[len] = carry_s;
}

__global__ __launch_bounds__(256) void fill_kernel(
    const int* __restrict__ i_idx, const int* __restrict__ p_idx,
    const int* __restrict__ row_p, const int* __restrict__ row_i,
    int* __restrict__ cur_p, int* __restrict__ cur_i,
    int* __restrict__ esrc_p, int* __restrict__ esrc_i, int E)
{
    const int e0 = (blockIdx.x * 256 + threadIdx.x) * 4;
    if (e0 >= E) return;
    int4 a = make_int4(0,0,0,0), b = make_int4(0,0,0,0);
    if (e0 + 3 < E) {
        a = *(const int4*)(i_idx + e0);
        b = *(const int4*)(p_idx + e0);
    } else {
        a.x = i_idx[e0]; b.x = p_idx[e0];
        if (e0 + 1 < E) { a.y = i_idx[e0 + 1]; b.y = p_idx[e0 + 1]; }
        if (e0 + 2 < E) { a.z = i_idx[e0 + 2]; b.z = p_idx[e0 + 2]; }
    }
    const int ii[4] = {a.x, a.y, a.z, a.w};
    const int pp[4] = {b.x, b.y, b.z, b.w};
    #pragma unroll
    for (int k = 0; k < 4; ++k) {
        if (e0 + k >= E) break;
        const int sp = atomicAdd(&cur_p[pp[k]], 1);
        esrc_p[row_p[pp[k]] + sp] = ii[k];
        const int si = atomicAdd(&cur_i[ii[k]], 1);
        esrc_i[row_i[ii[k]] + si] = pp[k];
    }
}

// ---------------- fused gather + GEMM + relu + residual + relu ----------------
// Block = 128 threads; thread j owns column j. R dest rows/block, gathered
// sequentially; edge loop 4-way unrolled with independent accumulators
// (4 scalar loads in flight per thread). msg in LDS; then H×H GEMM with
// float4 LDS broadcasts + coalesced W loads; relu + residual + relu.
template<int R>
__global__ __launch_bounds__(128) void gather_update_kernel(
    const float* __restrict__ src, const int* __restrict__ row,
    const int* __restrict__ esrc, const float* __restrict__ W,
    const float* __restrict__ b, float* __restrict__ hdst, int ndst)
{
    __shared__ float msg[R][HDIM];
    const int j = threadIdx.x;
    const int d0 = blockIdx.x * R;

    #pragma unroll
    for (int r = 0; r < R; ++r) {
        const int d = d0 + r;
        float a0 = 0.f, a1 = 0.f, a2 = 0.f, a3 = 0.f;
        if (d < ndst) {
            const int s0 = row[d], s1 = row[d + 1];
            int e = s0;
            for (; e + 3 < s1; e += 4) {            // 4 independent loads in flight
                const int i0 = esrc[e],     i1 = esrc[e + 1];
                const int i2 = esrc[e + 2], i3 = esrc[e + 3];
                a0 += src[(size_t)i0 * HDIM + j];
                a1 += src[(size_t)i1 * HDIM + j];
                a2 += src[(size_t)i2 * HDIM + j];
                a3 += src[(size_t)i3 * HDIM + j];
            }
            for (; e < s1; ++e)
                a0 += src[(size_t)esrc[e] * HDIM + j];
        }
        msg[r][j] = (a0 + a1) + (a2 + a3);
    }
    __syncthreads();

    float acc[R];
    const float bj = b[j];
    #pragma unroll
    for (int r = 0; r < R; ++r) acc[r] = bj;
    for (int kk = 0; kk < HDIM / 4; ++kk) {
        const float w0 = W[(kk * 4 + 0) * HDIM + j];   // coalesced, L2-resident
        const float w1 = W[(kk * 4 + 1) * HDIM + j];
        const float w2 = W[(kk * 4 + 2) * HDIM + j];
        const float w3 = W[(kk * 4 + 3) * HDIM + j];
        #pragma unroll
        for (int r = 0; r < R; ++r) {
            const float4 mv = ((const float4*)msg[r])[kk];   // LDS broadcast
            acc[r] = fmaf(mv.x, w0, acc[r]);
            acc[r] = fmaf(mv.y, w1, acc[r]);
            acc[r] = fmaf(mv.z, w2, acc[r]);
            acc[r] = fmaf(mv.w, w3, acc[r]);
        }
    }
    #pragma unroll
    for (int r = 0; r < R; ++r) {
        const int d = d0 + r;
        if (d < ndst) {
            const float upd = fmaxf(acc[r], 0.f);
            const float h = hdst[(size_t)d * HDIM + j];
            hdst[(size_t)d * HDIM + j] = fmaxf(h + upd, 0.f);
        }
    }
}

extern "C" void kernel_launch(void* const* d_in, const int* in_sizes, int n_in,
                              void* d_out, int out_size, void* d_ws, size_t ws_size,
                              hipStream_t stream)
{
    const float* item_feat = (const float*)d_in[0];   // [n,64]
    const float* pat_feat  = (const float*)d_in[1];   // [m,64]
    const int*   i_idx     = (const int*)d_in[2];     // [E]
    const int*   p_idx     = (const int*)d_in[3];     // [E]
    const float* W_item    = (const float*)d_in[4];
    const float* b_item    = (const float*)d_in[5];
    const float* W_pat     = (const float*)d_in[6];
    const float* b_pat     = (const float*)d_in[7];
    const float* W_i2p     = (const float*)d_in[8];
    const float* b_i2p     = (const float*)d_in[9];
    const float* W_p2i     = (const float*)d_in[10];
    const float* b_p2i     = (const float*)d_in[11];

    const int n = in_sizes[0] / 64;
    const int m = in_sizes[1] / 64;
    const int E = in_sizes[2];

    float* h_item = (float*)d_out;                    // [n,128]
    float* h_pat  = (float*)d_out + (size_t)n * HDIM; // [m,128]

    // ws (ints): [cur_p m][cur_i n][row_p m+1][row_i n+1][esrc_p E][esrc_i E]
    int* cur_p  = (int*)d_ws;
    int* cur_i  = cur_p + m;
    int* row_p  = cur_i + n;
    int* row_i  = row_p + (m + 1);
    int* esrc_p = row_i + (n + 1);
    int* esrc_i = esrc_p + E;

    constexpr int RG = 4;
    gemm_relu_kernel<64, RG><<<(n + RG - 1) / RG, 128, 0, stream>>>(
        item_feat, W_item, b_item, h_item, n);
    gemm_relu_kernel<64, RG><<<(m + RG - 1) / RG, 128, 0, stream>>>(
        pat_feat, W_pat, b_pat, h_pat, m);

    // ---- CSR build (once; indices static across rounds) ----
    const int e4blocks = (E + 1023) / 1024;
    hipMemsetAsync(cur_p, 0, (size_t)(m + n) * sizeof(int), stream);
    count_kernel<<<e4blocks, 256, 0, stream>>>(i_idx, p_idx, cur_i, cur_p, E);
    exscan2_kernel<<<2, 1024, 0, stream>>>(cur_p, row_p, m, cur_i, row_i, n);
    hipMemsetAsync(cur_p, 0, (size_t)(m + n) * sizeof(int), stream);
    fill_kernel<<<e4blocks, 256, 0, stream>>>(i_idx, p_idx, row_p, row_i,
                                              cur_p, cur_i, esrc_p, esrc_i, E);

    // ---- 2 rounds fused gather+GEMM+update ----
    constexpr int R = 8;
    for (int round = 0; round < 2; ++round) {
        gather_update_kernel<R><<<(m + R - 1) / R, 128, 0, stream>>>(
            h_item, row_p, esrc_p, W_i2p, b_i2p, h_pat, m);
        gather_update_kernel<R><<<(n + R - 1) / R, 128, 0, stream>>>(
            h_pat, row_i, esrc_i, W_p2i, b_p2i, h_item, n);
    }
}

// Round 5
// 764.563 us; speedup vs baseline: 2.9082x; 1.0479x over previous
//
#include <hip/hip_runtime.h>

// BranchingGNN, fp32 math. R5: gather from a bf16 shadow copy of the states
// (half the bytes AND half the load instructions: 64 lanes/row × bf16x2).
// fp32 state in d_out stays authoritative; bf16 copies live in d_ws and are
// written by the init GEMMs and the update epilogues. CSR build unchanged
// from R4 (fill's 128 MB scattered-write traffic is now the #1 dispatch).

static constexpr int HDIM = 128;

__device__ inline unsigned short f2bf_rne(float x) {
    unsigned u = __float_as_uint(x);
    u += 0x7FFFu + ((u >> 16) & 1u);        // round-to-nearest-even
    return (unsigned short)(u >> 16);
}
__device__ inline float bf_lo(unsigned u) { return __uint_as_float(u << 16); }
__device__ inline float bf_hi(unsigned u) { return __uint_as_float(u & 0xFFFF0000u); }

// ------------- initial projection: out = relu(X @ W + b), K=64; + bf16 copy ---
template<int K, int R>
__global__ __launch_bounds__(128) void gemm_relu_kernel(
    const float* __restrict__ X, const float* __restrict__ W,
    const float* __restrict__ b, float* __restrict__ out,
    unsigned short* __restrict__ outb, int nrows)
{
    __shared__ float xs[R][K];
    const int j = threadIdx.x;
    const int r0 = blockIdx.x * R;
    const int total = R * K;
    for (int t = j; t < total; t += 128) {
        const int rr = t / K, kk = t % K;
        const int r = r0 + rr;
        xs[rr][kk] = (r < nrows) ? X[(size_t)r * K + kk] : 0.f;
    }
    __syncthreads();
    float acc[R];
    const float bj = b[j];
    #pragma unroll
    for (int i = 0; i < R; ++i) acc[i] = bj;
    #pragma unroll 8
    for (int k = 0; k < K; ++k) {
        const float w = W[k * HDIM + j];
        #pragma unroll
        for (int i = 0; i < R; ++i) acc[i] = fmaf(xs[i][k], w, acc[i]);
    }
    #pragma unroll
    for (int i = 0; i < R; ++i) {
        const int r = r0 + i;
        if (r < nrows) {
            const float v = fmaxf(acc[i], 0.f);
            out[(size_t)r * HDIM + j] = v;
            outb[(size_t)r * HDIM + j] = f2bf_rne(v);
        }
    }
}

// ---------------- CSR build ---------------------------------------------------
__global__ __launch_bounds__(256) void count_kernel(
    const int* __restrict__ i_idx, const int* __restrict__ p_idx,
    int* __restrict__ cnt_i, int* __restrict__ cnt_p, int E)
{
    const int e = (blockIdx.x * 256 + threadIdx.x) * 4;
    if (e + 3 < E) {
        const int4 a = *(const int4*)(i_idx + e);
        const int4 b = *(const int4*)(p_idx + e);
        atomicAdd(&cnt_i[a.x], 1); atomicAdd(&cnt_i[a.y], 1);
        atomicAdd(&cnt_i[a.z], 1); atomicAdd(&cnt_i[a.w], 1);
        atomicAdd(&cnt_p[b.x], 1); atomicAdd(&cnt_p[b.y], 1);
        atomicAdd(&cnt_p[b.z], 1); atomicAdd(&cnt_p[b.w], 1);
    } else {
        for (int k = e; k < E; ++k) {
            atomicAdd(&cnt_i[i_idx[k]], 1);
            atomicAdd(&cnt_p[p_idx[k]], 1);
        }
    }
}

// Two independent single-block exclusive scans in one launch. out[len] = total.
__global__ __launch_bounds__(1024) void exscan2_kernel(
    const int* __restrict__ in0, int* __restrict__ out0, int len0,
    const int* __restrict__ in1, int* __restrict__ out1, int len1)
{
    const int* __restrict__ in  = blockIdx.x ? in1  : in0;
    int* __restrict__ out       = blockIdx.x ? out1 : out0;
    const int len               = blockIdx.x ? len1 : len0;

    __shared__ int wsum[16];
    __shared__ int carry_s;
    const int tid = threadIdx.x, lane = tid & 63, wid = tid >> 6;
    if (tid == 0) carry_s = 0;
    __syncthreads();
    for (int base = 0; base < len; base += 4096) {
        const int idx = base + tid * 4;
        int4 v = make_int4(0, 0, 0, 0);
        if (idx + 3 < len) {
            v = *(const int4*)(in + idx);
        } else if (idx < len) {
            v.x = in[idx];
            if (idx + 1 < len) v.y = in[idx + 1];
            if (idx + 2 < len) v.z = in[idx + 2];
        }
        const int s = v.x + v.y + v.z + v.w;
        int sc = s;
        #pragma unroll
        for (int off = 1; off < 64; off <<= 1) {
            const int t = __shfl_up(sc, off, 64);
            if (lane >= off) sc += t;
        }
        if (lane == 63) wsum[wid] = sc;
        __syncthreads();
        if (wid == 0) {
            const int ws = (lane < 16) ? wsum[lane] : 0;
            int wsc = ws;
            #pragma unroll
            for (int off = 1; off < 16; off <<= 1) {
                const int t = __shfl_up(wsc, off, 64);
                if (lane >= off) wsc += t;
            }
            if (lane < 16) wsum[lane] = wsc - ws;
        }
        __syncthreads();
        const int excl = carry_s + wsum[wid] + (sc - s);
        if (idx < len) {
            out[idx] = excl;
            if (idx + 1 < len) out[idx + 1] = excl + v.x;
            if (idx + 2 < len) out[idx + 2] = excl + v.x + v.y;
            if (idx + 3 < len) out[idx + 3] = excl + v.x + v.y + v.z;
        }
        __syncthreads();
        if (tid == 1023) carry_s = excl + s;
        __syncthreads();
    }
    if (tid == 0) out[len] = carry_s;
}

__global__ __launch_bounds__(256) void fill_kernel(
    const int* __restrict__ i_idx, const int* __restrict__ p_idx,
    const int* __restrict__ row_p, const int* __restrict__ row_i,
    int* __restrict__ cur_p, int* __restrict__ cur_i,
    int* __restrict__ esrc_p, int* __restrict__ esrc_i, int E)
{
    const int e0 = (blockIdx.x * 256 + threadIdx.x) * 4;
    if (e0 >= E) return;
    int4 a = make_int4(0,0,0,0), b = make_int4(0,0,0,0);
    if (e0 + 3 < E) {
        a = *(const int4*)(i_idx + e0);
        b = *(const int4*)(p_idx + e0);
    } else {
        a.x = i_idx[e0]; b.x = p_idx[e0];
        if (e0 + 1 < E) { a.y = i_idx[e0 + 1]; b.y = p_idx[e0 + 1]; }
        if (e0 + 2 < E) { a.z = i_idx[e0 + 2]; b.z = p_idx[e0 + 2]; }
    }
    const int ii[4] = {a.x, a.y, a.z, a.w};
    const int pp[4] = {b.x, b.y, b.z, b.w};
    #pragma unroll
    for (int k = 0; k < 4; ++k) {
        if (e0 + k >= E) break;
        const int sp = atomicAdd(&cur_p[pp[k]], 1);
        esrc_p[row_p[pp[k]] + sp] = ii[k];
        const int si = atomicAdd(&cur_i[ii[k]], 1);
        esrc_i[row_i[ii[k]] + si] = pp[k];
    }
}

// --------- fused bf16-gather + fp32 GEMM + relu + residual + relu -------------
// Block = 128 = 2 halves × 64 lanes. Gather: half h handles rows
// h*R/2..h*R/2+R/2-1; lane l loads the uint holding bf16 cols (2l, 2l+1);
// edge loop 4-way unrolled (4 loads in flight/thread). Per (row,edge) the
// block issues 64 loads instead of 128 and reads 256 B instead of 512 B.
// GEMM + residual in fp32 against the authoritative state; epilogue also
// refreshes the bf16 shadow (skipped for the final update).
template<int R, bool WRITE_BF>
__global__ __launch_bounds__(128) void gather_update_kernel(
    const unsigned short* __restrict__ srcb, const int* __restrict__ row,
    const int* __restrict__ esrc, const float* __restrict__ W,
    const float* __restrict__ b, float* __restrict__ hdst,
    unsigned short* __restrict__ dstb, int ndst)
{
    __shared__ float msg[R][HDIM];
    const int tid = threadIdx.x;
    const int half = tid >> 6;          // 0..1
    const int l = tid & 63;             // bf16-pair lane
    const int d0 = blockIdx.x * R;

    #pragma unroll
    for (int rr = 0; rr < R / 2; ++rr) {
        const int r = half * (R / 2) + rr;
        const int d = d0 + r;
        float x0 = 0.f, y0 = 0.f, x1 = 0.f, y1 = 0.f;
        float x2 = 0.f, y2 = 0.f, x3 = 0.f, y3 = 0.f;
        if (d < ndst) {
            const int s0 = row[d], s1 = row[d + 1];
            int e = s0;
            for (; e + 3 < s1; e += 4) {        // 4 independent loads in flight
                const int i0 = esrc[e],     i1 = esrc[e + 1];
                const int i2 = esrc[e + 2], i3 = esrc[e + 3];
                const unsigned u0 = ((const unsigned*)(srcb + (size_t)i0 * HDIM))[l];
                const unsigned u1 = ((const unsigned*)(srcb + (size_t)i1 * HDIM))[l];
                const unsigned u2 = ((const unsigned*)(srcb + (size_t)i2 * HDIM))[l];
                const unsigned u3 = ((const unsigned*)(srcb + (size_t)i3 * HDIM))[l];
                x0 += bf_lo(u0); y0 += bf_hi(u0);
                x1 += bf_lo(u1); y1 += bf_hi(u1);
                x2 += bf_lo(u2); y2 += bf_hi(u2);
                x3 += bf_lo(u3); y3 += bf_hi(u3);
            }
            for (; e < s1; ++e) {
                const unsigned u = ((const unsigned*)(srcb + (size_t)esrc[e] * HDIM))[l];
                x0 += bf_lo(u); y0 += bf_hi(u);
            }
        }
        float2 mv;
        mv.x = (x0 + x1) + (x2 + x3);
        mv.y = (y0 + y1) + (y2 + y3);
        ((float2*)msg[r])[l] = mv;
    }
    __syncthreads();

    const int j = tid;                   // column 0..127
    float acc[R];
    const float bj = b[j];
    #pragma unroll
    for (int r = 0; r < R; ++r) acc[r] = bj;
    for (int kk = 0; kk < HDIM / 4; ++kk) {
        const float w0 = W[(kk * 4 + 0) * HDIM + j];
        const float w1 = W[(kk * 4 + 1) * HDIM + j];
        const float w2 = W[(kk * 4 + 2) * HDIM + j];
        const float w3 = W[(kk * 4 + 3) * HDIM + j];
        #pragma unroll
        for (int r = 0; r < R; ++r) {
            const float4 mv = ((const float4*)msg[r])[kk];   // LDS broadcast
            acc[r] = fmaf(mv.x, w0, acc[r]);
            acc[r] = fmaf(mv.y, w1, acc[r]);
            acc[r] = fmaf(mv.z, w2, acc[r]);
            acc[r] = fmaf(mv.w, w3, acc[r]);
        }
    }
    #pragma unroll
    for (int r = 0; r < R; ++r) {
        const int d = d0 + r;
        if (d < ndst) {
            const float upd = fmaxf(acc[r], 0.f);
            const float h = hdst[(size_t)d * HDIM + j];
            const float res = fmaxf(h + upd, 0.f);
            hdst[(size_t)d * HDIM + j] = res;
            if (WRITE_BF) dstb[(size_t)d * HDIM + j] = f2bf_rne(res);
        }
    }
}

extern "C" void kernel_launch(void* const* d_in, const int* in_sizes, int n_in,
                              void* d_out, int out_size, void* d_ws, size_t ws_size,
                              hipStream_t stream)
{
    const float* item_feat = (const float*)d_in[0];   // [n,64]
    const float* pat_feat  = (const float*)d_in[1];   // [m,64]
    const int*   i_idx     = (const int*)d_in[2];     // [E]
    const int*   p_idx     = (const int*)d_in[3];     // [E]
    const float* W_item    = (const float*)d_in[4];
    const float* b_item    = (const float*)d_in[5];
    const float* W_pat     = (const float*)d_in[6];
    const float* b_pat     = (const float*)d_in[7];
    const float* W_i2p     = (const float*)d_in[8];
    const float* b_i2p     = (const float*)d_in[9];
    const float* W_p2i     = (const float*)d_in[10];
    const float* b_p2i     = (const float*)d_in[11];

    const int n = in_sizes[0] / 64;
    const int m = in_sizes[1] / 64;
    const int E = in_sizes[2];

    float* h_item = (float*)d_out;                    // [n,128] fp32 (output)
    float* h_pat  = (float*)d_out + (size_t)n * HDIM; // [m,128]

    // ws: [h_item_bf n*128 u16][h_pat_bf m*128 u16][cur_p m][cur_i n]
    //     [row_p m+1][row_i n+1][esrc_p E][esrc_i E]
    unsigned short* hib = (unsigned short*)d_ws;
    unsigned short* hpb = hib + (size_t)n * HDIM;
    int* cur_p  = (int*)(hpb + (size_t)m * HDIM);
    int* cur_i  = cur_p + m;
    int* row_p  = cur_i + n;
    int* row_i  = row_p + (m + 1);
    int* esrc_p = row_i + (n + 1);
    int* esrc_i = esrc_p + E;

    constexpr int RG = 4;
    gemm_relu_kernel<64, RG><<<(n + RG - 1) / RG, 128, 0, stream>>>(
        item_feat, W_item, b_item, h_item, hib, n);
    gemm_relu_kernel<64, RG><<<(m + RG - 1) / RG, 128, 0, stream>>>(
        pat_feat, W_pat, b_pat, h_pat, hpb, m);

    // ---- CSR build (once; indices static across rounds) ----
    const int e4blocks = (E + 1023) / 1024;
    hipMemsetAsync(cur_p, 0, (size_t)(m + n) * sizeof(int), stream);
    count_kernel<<<e4blocks, 256, 0, stream>>>(i_idx, p_idx, cur_i, cur_p, E);
    exscan2_kernel<<<2, 1024, 0, stream>>>(cur_p, row_p, m, cur_i, row_i, n);
    hipMemsetAsync(cur_p, 0, (size_t)(m + n) * sizeof(int), stream);
    fill_kernel<<<e4blocks, 256, 0, stream>>>(i_idx, p_idx, row_p, row_i,
                                              cur_p, cur_i, esrc_p, esrc_i, E);

    // ---- 2 rounds fused gather+GEMM+update (bf16 gather source) ----
    constexpr int R = 8;
    // round 1
    gather_update_kernel<R, true><<<(m + R - 1) / R, 128, 0, stream>>>(
        hib, row_p, esrc_p, W_i2p, b_i2p, h_pat, hpb, m);
    gather_update_kernel<R, true><<<(n + R - 1) / R, 128, 0, stream>>>(
        hpb, row_i, esrc_i, W_p2i, b_p2i, h_item, hib, n);
    // round 2 (final item update needs no bf16 shadow)
    gather_update_kernel<R, true><<<(m + R - 1) / R, 128, 0, stream>>>(
        hib, row_p, esrc_p, W_i2p, b_i2p, h_pat, hpb, m);
    gather_update_kernel<R, false><<<(n + R - 1) / R, 128, 0, stream>>>(
        hpb, row_i, esrc_i, W_p2i, b_p2i, h_item, hib, n);
}

// Round 6
// 632.231 us; speedup vs baseline: 3.5169x; 1.2093x over previous
//
#include <hip/hip_runtime.h>

// BranchingGNN, fp32 math, bf16 gather source. R6: test the latency hypothesis —
// 8 independent gather loads in flight per thread (vs 4) and NO serialized
// remainder: edge batches are padded with a sentinel all-zero source row
// (index nsrc), selected scalar-side before the vmem load. esrc arrays have
// +8 ints slack so speculative index reads never fault.

static constexpr int HDIM = 128;

__device__ inline unsigned short f2bf_rne(float x) {
    unsigned u = __float_as_uint(x);
    u += 0x7FFFu + ((u >> 16) & 1u);        // round-to-nearest-even
    return (unsigned short)(u >> 16);
}
__device__ inline float bf_lo(unsigned u) { return __uint_as_float(u << 16); }
__device__ inline float bf_hi(unsigned u) { return __uint_as_float(u & 0xFFFF0000u); }

// ------------- initial projection: out = relu(X @ W + b), K=64; + bf16 copy ---
template<int K, int R>
__global__ __launch_bounds__(128) void gemm_relu_kernel(
    const float* __restrict__ X, const float* __restrict__ W,
    const float* __restrict__ b, float* __restrict__ out,
    unsigned short* __restrict__ outb, int nrows)
{
    __shared__ float xs[R][K];
    const int j = threadIdx.x;
    const int r0 = blockIdx.x * R;
    const int total = R * K;
    for (int t = j; t < total; t += 128) {
        const int rr = t / K, kk = t % K;
        const int r = r0 + rr;
        xs[rr][kk] = (r < nrows) ? X[(size_t)r * K + kk] : 0.f;
    }
    __syncthreads();
    float acc[R];
    const float bj = b[j];
    #pragma unroll
    for (int i = 0; i < R; ++i) acc[i] = bj;
    #pragma unroll 8
    for (int k = 0; k < K; ++k) {
        const float w = W[k * HDIM + j];
        #pragma unroll
        for (int i = 0; i < R; ++i) acc[i] = fmaf(xs[i][k], w, acc[i]);
    }
    #pragma unroll
    for (int i = 0; i < R; ++i) {
        const int r = r0 + i;
        if (r < nrows) {
            const float v = fmaxf(acc[i], 0.f);
            out[(size_t)r * HDIM + j] = v;
            outb[(size_t)r * HDIM + j] = f2bf_rne(v);
        }
    }
}

// ---------------- CSR build ---------------------------------------------------
__global__ __launch_bounds__(256) void count_kernel(
    const int* __restrict__ i_idx, const int* __restrict__ p_idx,
    int* __restrict__ cnt_i, int* __restrict__ cnt_p, int E)
{
    const int e = (blockIdx.x * 256 + threadIdx.x) * 4;
    if (e + 3 < E) {
        const int4 a = *(const int4*)(i_idx + e);
        const int4 b = *(const int4*)(p_idx + e);
        atomicAdd(&cnt_i[a.x], 1); atomicAdd(&cnt_i[a.y], 1);
        atomicAdd(&cnt_i[a.z], 1); atomicAdd(&cnt_i[a.w], 1);
        atomicAdd(&cnt_p[b.x], 1); atomicAdd(&cnt_p[b.y], 1);
        atomicAdd(&cnt_p[b.z], 1); atomicAdd(&cnt_p[b.w], 1);
    } else {
        for (int k = e; k < E; ++k) {
            atomicAdd(&cnt_i[i_idx[k]], 1);
            atomicAdd(&cnt_p[p_idx[k]], 1);
        }
    }
}

// Two independent single-block exclusive scans in one launch. out[len] = total.
__global__ __launch_bounds__(1024) void exscan2_kernel(
    const int* __restrict__ in0, int* __restrict__ out0, int len0,
    const int* __restrict__ in1, int* __restrict__ out1, int len1)
{
    const int* __restrict__ in  = blockIdx.x ? in1  : in0;
    int* __restrict__ out       = blockIdx.x ? out1 : out0;
    const int len               = blockIdx.x ? len1 : len0;

    __shared__ int wsum[16];
    __shared__ int carry_s;
    const int tid = threadIdx.x, lane = tid & 63, wid = tid >> 6;
    if (tid == 0) carry_s = 0;
    __syncthreads();
    for (int base = 0; base < len; base += 4096) {
        const int idx = base + tid * 4;
        int4 v = make_int4(0, 0, 0, 0);
        if (idx + 3 < len) {
            v = *(const int4*)(in + idx);
        } else if (idx < len) {
            v.x = in[idx];
            if (idx + 1 < len) v.y = in[idx + 1];
            if (idx + 2 < len) v.z = in[idx + 2];
        }
        const int s = v.x + v.y + v.z + v.w;
        int sc = s;
        #pragma unroll
        for (int off = 1; off < 64; off <<= 1) {
            const int t = __shfl_up(sc, off, 64);
            if (lane >= off) sc += t;
        }
        if (lane == 63) wsum[wid] = sc;
        __syncthreads();
        if (wid == 0) {
            const int ws = (lane < 16) ? wsum[lane] : 0;
            int wsc = ws;
            #pragma unroll
            for (int off = 1; off < 16; off <<= 1) {
                const int t = __shfl_up(wsc, off, 64);
                if (lane >= off) wsc += t;
            }
            if (lane < 16) wsum[lane] = wsc - ws;
        }
        __syncthreads();
        const int excl = carry_s + wsum[wid] + (sc - s);
        if (idx < len) {
            out[idx] = excl;
            if (idx + 1 < len) out[idx + 1] = excl + v.x;
            if (idx + 2 < len) out[idx + 2] = excl + v.x + v.y;
            if (idx + 3 < len) out[idx + 3] = excl + v.x + v.y + v.z;
        }
        __syncthreads();
        if (tid == 1023) carry_s = excl + s;
        __syncthreads();
    }
    if (tid == 0) out[len] = carry_s;
}

__global__ __launch_bounds__(256) void fill_kernel(
    const int* __restrict__ i_idx, const int* __restrict__ p_idx,
    const int* __restrict__ row_p, const int* __restrict__ row_i,
    int* __restrict__ cur_p, int* __restrict__ cur_i,
    int* __restrict__ esrc_p, int* __restrict__ esrc_i, int E)
{
    const int e0 = (blockIdx.x * 256 + threadIdx.x) * 4;
    if (e0 >= E) return;
    int4 a = make_int4(0,0,0,0), b = make_int4(0,0,0,0);
    if (e0 + 3 < E) {
        a = *(const int4*)(i_idx + e0);
        b = *(const int4*)(p_idx + e0);
    } else {
        a.x = i_idx[e0]; b.x = p_idx[e0];
        if (e0 + 1 < E) { a.y = i_idx[e0 + 1]; b.y = p_idx[e0 + 1]; }
        if (e0 + 2 < E) { a.z = i_idx[e0 + 2]; b.z = p_idx[e0 + 2]; }
    }
    const int ii[4] = {a.x, a.y, a.z, a.w};
    const int pp[4] = {b.x, b.y, b.z, b.w};
    #pragma unroll
    for (int k = 0; k < 4; ++k) {
        if (e0 + k >= E) break;
        const int sp = atomicAdd(&cur_p[pp[k]], 1);
        esrc_p[row_p[pp[k]] + sp] = ii[k];
        const int si = atomicAdd(&cur_i[ii[k]], 1);
        esrc_i[row_i[ii[k]] + si] = pp[k];
    }
}

// --------- fused bf16-gather + fp32 GEMM + relu + residual + relu -------------
// Block = 128 = 2 waves × 64 lanes. Wave h gathers rows h*R/2..h*R/2+R/2-1;
// lane l loads the uint holding bf16 cols (2l,2l+1). Edge loop: ceil(deg/8)
// full batches of 8 independent loads; out-of-range slots select the sentinel
// zero row `zr` (scalar cselect before the vmem load; esrc has +8 slack).
template<int R, bool WRITE_BF>
__global__ __launch_bounds__(128) void gather_update_kernel(
    const unsigned short* __restrict__ srcb, const int* __restrict__ row,
    const int* __restrict__ esrc, const float* __restrict__ W,
    const float* __restrict__ b, float* __restrict__ hdst,
    unsigned short* __restrict__ dstb, int ndst, int zr)
{
    __shared__ float msg[R][HDIM];
    const int tid = threadIdx.x;
    const int half = tid >> 6;          // 0..1 (wave id)
    const int l = tid & 63;             // bf16-pair lane
    const int d0 = blockIdx.x * R;

    #pragma unroll
    for (int rr = 0; rr < R / 2; ++rr) {
        const int r = half * (R / 2) + rr;
        const int d = d0 + r;
        float x0=0.f,y0=0.f,x1=0.f,y1=0.f,x2=0.f,y2=0.f,x3=0.f,y3=0.f;
        float x4=0.f,y4=0.f,x5=0.f,y5=0.f,x6=0.f,y6=0.f,x7=0.f,y7=0.f;
        if (d < ndst) {
            const int s0 = row[d], s1 = row[d + 1];
            for (int e = s0; e < s1; e += 8) {   // full batches, sentinel-padded
                // indices are wave-uniform: scalar loads + scalar selects
                const int i0 = (e + 0 < s1) ? esrc[e + 0] : zr;
                const int i1 = (e + 1 < s1) ? esrc[e + 1] : zr;
                const int i2 = (e + 2 < s1) ? esrc[e + 2] : zr;
                const int i3 = (e + 3 < s1) ? esrc[e + 3] : zr;
                const int i4 = (e + 4 < s1) ? esrc[e + 4] : zr;
                const int i5 = (e + 5 < s1) ? esrc[e + 5] : zr;
                const int i6 = (e + 6 < s1) ? esrc[e + 6] : zr;
                const int i7 = (e + 7 < s1) ? esrc[e + 7] : zr;
                const unsigned u0 = ((const unsigned*)(srcb + (size_t)i0 * HDIM))[l];
                const unsigned u1 = ((const unsigned*)(srcb + (size_t)i1 * HDIM))[l];
                const unsigned u2 = ((const unsigned*)(srcb + (size_t)i2 * HDIM))[l];
                const unsigned u3 = ((const unsigned*)(srcb + (size_t)i3 * HDIM))[l];
                const unsigned u4 = ((const unsigned*)(srcb + (size_t)i4 * HDIM))[l];
                const unsigned u5 = ((const unsigned*)(srcb + (size_t)i5 * HDIM))[l];
                const unsigned u6 = ((const unsigned*)(srcb + (size_t)i6 * HDIM))[l];
                const unsigned u7 = ((const unsigned*)(srcb + (size_t)i7 * HDIM))[l];
                x0 += bf_lo(u0); y0 += bf_hi(u0);
                x1 += bf_lo(u1); y1 += bf_hi(u1);
                x2 += bf_lo(u2); y2 += bf_hi(u2);
                x3 += bf_lo(u3); y3 += bf_hi(u3);
                x4 += bf_lo(u4); y4 += bf_hi(u4);
                x5 += bf_lo(u5); y5 += bf_hi(u5);
                x6 += bf_lo(u6); y6 += bf_hi(u6);
                x7 += bf_lo(u7); y7 += bf_hi(u7);
            }
        }
        float2 mv;
        mv.x = ((x0 + x1) + (x2 + x3)) + ((x4 + x5) + (x6 + x7));
        mv.y = ((y0 + y1) + (y2 + y3)) + ((y4 + y5) + (y6 + y7));
        ((float2*)msg[r])[l] = mv;
    }
    __syncthreads();

    const int j = tid;                   // column 0..127
    float acc[R];
    const float bj = b[j];
    #pragma unroll
    for (int r = 0; r < R; ++r) acc[r] = bj;
    for (int kk = 0; kk < HDIM / 4; ++kk) {
        const float w0 = W[(kk * 4 + 0) * HDIM + j];
        const float w1 = W[(kk * 4 + 1) * HDIM + j];
        const float w2 = W[(kk * 4 + 2) * HDIM + j];
        const float w3 = W[(kk * 4 + 3) * HDIM + j];
        #pragma unroll
        for (int r = 0; r < R; ++r) {
            const float4 mv = ((const float4*)msg[r])[kk];   // LDS broadcast
            acc[r] = fmaf(mv.x, w0, acc[r]);
            acc[r] = fmaf(mv.y, w1, acc[r]);
            acc[r] = fmaf(mv.z, w2, acc[r]);
            acc[r] = fmaf(mv.w, w3, acc[r]);
        }
    }
    #pragma unroll
    for (int r = 0; r < R; ++r) {
        const int d = d0 + r;
        if (d < ndst) {
            const float upd = fmaxf(acc[r], 0.f);
            const float h = hdst[(size_t)d * HDIM + j];
            const float res = fmaxf(h + upd, 0.f);
            hdst[(size_t)d * HDIM + j] = res;
            if (WRITE_BF) dstb[(size_t)d * HDIM + j] = f2bf_rne(res);
        }
    }
}

extern "C" void kernel_launch(void* const* d_in, const int* in_sizes, int n_in,
                              void* d_out, int out_size, void* d_ws, size_t ws_size,
                              hipStream_t stream)
{
    const float* item_feat = (const float*)d_in[0];   // [n,64]
    const float* pat_feat  = (const float*)d_in[1];   // [m,64]
    const int*   i_idx     = (const int*)d_in[2];     // [E]
    const int*   p_idx     = (const int*)d_in[3];     // [E]
    const float* W_item    = (const float*)d_in[4];
    const float* b_item    = (const float*)d_in[5];
    const float* W_pat     = (const float*)d_in[6];
    const float* b_pat     = (const float*)d_in[7];
    const float* W_i2p     = (const float*)d_in[8];
    const float* b_i2p     = (const float*)d_in[9];
    const float* W_p2i     = (const float*)d_in[10];
    const float* b_p2i     = (const float*)d_in[11];

    const int n = in_sizes[0] / 64;
    const int m = in_sizes[1] / 64;
    const int E = in_sizes[2];

    float* h_item = (float*)d_out;                    // [n,128] fp32 (output)
    float* h_pat  = (float*)d_out + (size_t)n * HDIM; // [m,128]

    // ws: [h_item_bf (n+1)*128 u16][h_pat_bf (m+1)*128 u16][cur_p m][cur_i n]
    //     [row_p m+1][row_i n+1][esrc_p E+8][esrc_i E+8]
    unsigned short* hib = (unsigned short*)d_ws;              // rows 0..n (n = zero row)
    unsigned short* hpb = hib + (size_t)(n + 1) * HDIM;       // rows 0..m (m = zero row)
    int* cur_p  = (int*)(hpb + (size_t)(m + 1) * HDIM);
    int* cur_i  = cur_p + m;
    int* row_p  = cur_i + n;
    int* row_i  = row_p + (m + 1);
    int* esrc_p = row_i + (n + 1);
    int* esrc_i = esrc_p + (E + 8);

    // zero the sentinel rows (re-poisoned to 0xAA before every timed call)
    hipMemsetAsync(hib + (size_t)n * HDIM, 0, HDIM * sizeof(unsigned short), stream);
    hipMemsetAsync(hpb + (size_t)m * HDIM, 0, HDIM * sizeof(unsigned short), stream);

    constexpr int RG = 4;
    gemm_relu_kernel<64, RG><<<(n + RG - 1) / RG, 128, 0, stream>>>(
        item_feat, W_item, b_item, h_item, hib, n);
    gemm_relu_kernel<64, RG><<<(m + RG - 1) / RG, 128, 0, stream>>>(
        pat_feat, W_pat, b_pat, h_pat, hpb, m);

    // ---- CSR build (once; indices static across rounds) ----
    const int e4blocks = (E + 1023) / 1024;
    hipMemsetAsync(cur_p, 0, (size_t)(m + n) * sizeof(int), stream);
    count_kernel<<<e4blocks, 256, 0, stream>>>(i_idx, p_idx, cur_i, cur_p, E);
    exscan2_kernel<<<2, 1024, 0, stream>>>(cur_p, row_p, m, cur_i, row_i, n);
    hipMemsetAsync(cur_p, 0, (size_t)(m + n) * sizeof(int), stream);
    fill_kernel<<<e4blocks, 256, 0, stream>>>(i_idx, p_idx, row_p, row_i,
                                              cur_p, cur_i, esrc_p, esrc_i, E);

    // ---- 2 rounds fused gather+GEMM+update (bf16 gather source) ----
    constexpr int R = 8;
    // round 1
    gather_update_kernel<R, true><<<(m + R - 1) / R, 128, 0, stream>>>(
        hib, row_p, esrc_p, W_i2p, b_i2p, h_pat, hpb, m, n);
    gather_update_kernel<R, true><<<(n + R - 1) / R, 128, 0, stream>>>(
        hpb, row_i, esrc_i, W_p2i, b_p2i, h_item, hib, n, m);
    // round 2 (final item update needs no bf16 shadow)
    gather_update_kernel<R, true><<<(m + R - 1) / R, 128, 0, stream>>>(
        hib, row_p, esrc_p, W_i2p, b_i2p, h_pat, hpb, m, n);
    gather_update_kernel<R, false><<<(n + R - 1) / R, 128, 0, stream>>>(
        hpb, row_i, esrc_i, W_p2i, b_p2i, h_item, hib, n, m);
}